// Round 12
// baseline (217.486 us; speedup 1.0000x reference)
//
#include <hip/hip_runtime.h>
#include <math.h>

#define N_NODES 50000
#define D       64
#define N_EDGES 800000
#define N_HEAD  4

typedef unsigned short ushort_t;
typedef unsigned int   uint_t;

// bf16 <-> fp32 bit helpers (RNE on pack)
__device__ __forceinline__ float bf_lo(uint_t u) {
    return __uint_as_float(u << 16);
}
__device__ __forceinline__ float bf_hi(uint_t u) {
    return __uint_as_float(u & 0xffff0000u);
}
__device__ __forceinline__ ushort_t f2bf(float f) {
    uint_t u = __float_as_uint(f);
    u += 0x7fffu + ((u >> 16) & 1u);   // round-to-nearest-even
    return (ushort_t)(u >> 16);
}

// ---------------------------------------------------------------------------
// prep: cv[e] = (col<<16) | bf16(val)  (col < 50000 fits 16 bits);
//       row_ptr[r] = lower_bound(edge_row, r) (edge_row sorted)
// ---------------------------------------------------------------------------
__global__ void prep_kernel(const int* __restrict__ edge_row,
                            const int* __restrict__ edge_col,
                            const float* __restrict__ edge_val,
                            int* __restrict__ row_ptr,
                            uint_t* __restrict__ cv) {
    const int i = blockIdx.x * blockDim.x + threadIdx.x;
    if (i < N_EDGES)
        cv[i] = ((uint_t)edge_col[i] << 16) | (uint_t)f2bf(edge_val[i]);
    if (i <= N_NODES) {
        int lo = 0, hi = N_EDGES;
        while (lo < hi) {
            int mid = (lo + hi) >> 1;
            if (edge_row[mid] < i) lo = mid + 1; else hi = mid;
        }
        row_ptr[i] = lo;
    }
}

// ---------------------------------------------------------------------------
// head-0 linear: t[n][j] = bf16( elu( sum_k (mask? x[n][k]:0)*W[j][k] + b[j] ) )
// lane j holds W[j][*] in 64 VGPRs; row data via wave-uniform scalar loads.
// ---------------------------------------------------------------------------
__global__ __launch_bounds__(256) void linear_elu_kernel(
        const float* __restrict__ in,
        const float* __restrict__ W,
        const float* __restrict__ b,
        const int*  __restrict__ et,
        ushort_t* __restrict__ t) {
    const int lane = threadIdx.x & 63;
    const int wid  = (blockIdx.x * blockDim.x + threadIdx.x) >> 6;
    const int nwav = (gridDim.x * blockDim.x) >> 6;

    float4 w4[16];
    {
        const float4* wp = (const float4*)(W + lane * D);
        #pragma unroll
        for (int i = 0; i < 16; ++i) w4[i] = wp[i];
    }
    const float* w = (const float*)w4;
    const float bj = b[lane];

    for (int row0 = wid; row0 < N_NODES; row0 += nwav) {
        const int row = __builtin_amdgcn_readfirstlane(row0);
        float acc = bj;
        if (et[row] != 0) {
            const float* rp = in + (size_t)row * D;
            #pragma unroll
            for (int k = 0; k < D; ++k)
                acc = fmaf(rp[k], w[k], acc);
        }
        const float e = (acc > 0.f) ? acc : expm1f(acc);
        t[(size_t)row * D + lane] = f2bf(e);
    }
}

// ---------------------------------------------------------------------------
// Fused spmm + next-head linear. Multi-row strided loop with a LARGE grid
// (R11 ran 4096 waves -> 20% occupancy -> gather latency exposed; R6 ran
// 1 row/wave -> 800 MB W reload traffic. 16384 waves / ~3 rows per wave is
// the bracket optimum: W traffic 256 MB L2-resident, occupancy ~50%).
// Per row: R7's exact gather structure, XOR-reduce, out (+)= in fp32, then
// epilogue broadcasts the fp32 h-row via per-wave LDS and all 64 lanes run
// the next head's linear+ELU. h never touches global memory.
// ---------------------------------------------------------------------------
template<int FIRST, int DO_LINEAR>
__global__ __launch_bounds__(256) void fused_kernel(
        const ushort_t* __restrict__ tin,   // bf16 [N][64]
        ushort_t* __restrict__ tout,        // bf16 [N][64]
        const float* __restrict__ W,        // next head's W
        const float* __restrict__ bvec,
        const uint_t* __restrict__ cv,      // (col<<16)|bf16(val)
        const int*  __restrict__ row_ptr,
        float* __restrict__ out) {
    __shared__ float rowbuf[4][64];
    const int tid   = threadIdx.x;
    const int lane  = tid & 63;
    const int wslot = tid >> 6;
    const int g     = lane >> 4;
    const int l     = lane & 15;
    const int wid   = (blockIdx.x * blockDim.x + tid) >> 6;
    const int nwav  = (gridDim.x * blockDim.x) >> 6;

    float4 w4[16];
    float bj = 0.f;
    if (DO_LINEAR) {
        const float4* wp = (const float4*)(W + lane * D);
        #pragma unroll
        for (int i = 0; i < 16; ++i) w4[i] = wp[i];
        bj = bvec[lane];
    }
    const float* w = (const float*)w4;

    for (int row0 = wid; row0 < N_NODES; row0 += nwav) {
        const int row = __builtin_amdgcn_readfirstlane(row0);
        const size_t base = (size_t)row * D + (size_t)l * 4;

        const int e0 = row_ptr[row];
        const int e1 = row_ptr[row + 1];
        const int eclamp = (e1 > 0) ? e1 - 1 : 0;
        const bool haveB = (e0 + 16) < e1;   // wave-uniform

        float4 oldo = {0.f, 0.f, 0.f, 0.f};
        if (!FIRST && g == 0) oldo = *(const float4*)(out + base);

        int   cA[4], cB[4];
        float vA[4], vB[4];
        #pragma unroll
        for (int u = 0; u < 4; ++u) {
            const int  ce = e0 + 4 * u + g;
            const bool ok = ce < e1;
            const uint_t p = cv[ok ? ce : eclamp];
            cA[u] = (int)(p >> 16);
            vA[u] = ok ? bf_lo(p) : 0.f;
        }
        if (haveB) {
            #pragma unroll
            for (int u = 0; u < 4; ++u) {
                const int  ce = e0 + 16 + 4 * u + g;
                const bool ok = ce < e1;
                const uint_t p = cv[ok ? ce : eclamp];
                cB[u] = (int)(p >> 16);
                vB[u] = ok ? bf_lo(p) : 0.f;
            }
        }

        uint2 rA[4], rB[4];
        #pragma unroll
        for (int u = 0; u < 4; ++u)
            rA[u] = *(const uint2*)(tin + (size_t)cA[u] * D + l * 4);
        if (haveB) {
            #pragma unroll
            for (int u = 0; u < 4; ++u)
                rB[u] = *(const uint2*)(tin + (size_t)cB[u] * D + l * 4);
        }

        float4 acc = {0.f, 0.f, 0.f, 0.f};
        #pragma unroll
        for (int u = 0; u < 4; ++u) {
            acc.x = fmaf(vA[u], bf_lo(rA[u].x), acc.x);
            acc.y = fmaf(vA[u], bf_hi(rA[u].x), acc.y);
            acc.z = fmaf(vA[u], bf_lo(rA[u].y), acc.z);
            acc.w = fmaf(vA[u], bf_hi(rA[u].y), acc.w);
        }
        if (haveB) {
            #pragma unroll
            for (int u = 0; u < 4; ++u) {
                acc.x = fmaf(vB[u], bf_lo(rB[u].x), acc.x);
                acc.y = fmaf(vB[u], bf_hi(rB[u].x), acc.y);
                acc.z = fmaf(vB[u], bf_lo(rB[u].y), acc.z);
                acc.w = fmaf(vB[u], bf_hi(rB[u].y), acc.w);
            }
        }
        // rare tail: deg > 32
        for (int e = e0 + 32; e < e1; e += 16) {
            #pragma unroll
            for (int u = 0; u < 4; ++u) {
                const int  ce = e + 4 * u + g;
                const bool ok = ce < e1;
                const uint_t p = cv[ok ? ce : eclamp];
                const int   c = (int)(p >> 16);
                const float v = ok ? bf_lo(p) : 0.f;
                const uint2 r = *(const uint2*)(tin + (size_t)c * D + l * 4);
                acc.x = fmaf(v, bf_lo(r.x), acc.x);
                acc.y = fmaf(v, bf_hi(r.x), acc.y);
                acc.z = fmaf(v, bf_lo(r.y), acc.z);
                acc.w = fmaf(v, bf_hi(r.y), acc.w);
            }
        }

        // reduce across the 4 groups (lane bits 4,5)
        #pragma unroll
        for (int off = 16; off < 64; off <<= 1) {
            acc.x += __shfl_xor(acc.x, off, 64);
            acc.y += __shfl_xor(acc.y, off, 64);
            acc.z += __shfl_xor(acc.z, off, 64);
            acc.w += __shfl_xor(acc.w, off, 64);
        }

        if (g == 0) {
            float4 o;
            o.x = acc.x + oldo.x; o.y = acc.y + oldo.y;
            o.z = acc.z + oldo.z; o.w = acc.w + oldo.w;
            *(float4*)(out + base) = o;
            if (DO_LINEAR)
                *(float4*)&rowbuf[wslot][l * 4] =
                    make_float4(acc.x, acc.y, acc.z, acc.w);
        }

        if (DO_LINEAR) {
            // same-wave LDS RAW: compiler inserts lgkmcnt wait (R6/R11-proven)
            float lacc = bj;
            #pragma unroll
            for (int k = 0; k < 16; ++k) {
                const float4 r = *(const float4*)&rowbuf[wslot][k * 4];
                lacc = fmaf(r.x, w[4 * k + 0], lacc);
                lacc = fmaf(r.y, w[4 * k + 1], lacc);
                lacc = fmaf(r.z, w[4 * k + 2], lacc);
                lacc = fmaf(r.w, w[4 * k + 3], lacc);
            }
            const float eo = (lacc > 0.f) ? lacc : expm1f(lacc);
            tout[(size_t)row * D + lane] = f2bf(eo);
        }
    }
}

// ---------------------------------------------------------------------------
// head-4 spmm (no linear epilogue) — unmodified R7 structure, 1 row/wave.
// ---------------------------------------------------------------------------
__global__ __launch_bounds__(256) void spmm_kernel(
        const ushort_t* __restrict__ tin,
        const uint_t* __restrict__ cv,
        const int*   __restrict__ row_ptr,
        float* __restrict__ out) {
    const int lane = threadIdx.x & 63;
    const int g    = lane >> 4;
    const int l    = lane & 15;
    const int row0 = (blockIdx.x * blockDim.x + threadIdx.x) >> 6;
    if (row0 >= N_NODES) return;
    const int row = __builtin_amdgcn_readfirstlane(row0);

    const int e0 = row_ptr[row];
    const int e1 = row_ptr[row + 1];
    const int eclamp = (e1 > 0) ? e1 - 1 : 0;
    float4 acc = {0.f, 0.f, 0.f, 0.f};

    int   cA[4], cB[4];
    float vA[4], vB[4];
    uint2 rA[4], rB[4];
    const bool haveB = (e0 + 16) < e1;

    #pragma unroll
    for (int u = 0; u < 4; ++u) {
        const int  ce = e0 + 4 * u + g;
        const bool ok = ce < e1;
        const uint_t p = cv[ok ? ce : eclamp];
        cA[u] = (int)(p >> 16);
        vA[u] = ok ? bf_lo(p) : 0.f;
    }
    if (haveB) {
        #pragma unroll
        for (int u = 0; u < 4; ++u) {
            const int  ce = e0 + 16 + 4 * u + g;
            const bool ok = ce < e1;
            const uint_t p = cv[ok ? ce : eclamp];
            cB[u] = (int)(p >> 16);
            vB[u] = ok ? bf_lo(p) : 0.f;
        }
    }
    #pragma unroll
    for (int u = 0; u < 4; ++u)
        rA[u] = *(const uint2*)(tin + (size_t)cA[u] * D + l * 4);
    if (haveB) {
        #pragma unroll
        for (int u = 0; u < 4; ++u)
            rB[u] = *(const uint2*)(tin + (size_t)cB[u] * D + l * 4);
    }
    #pragma unroll
    for (int u = 0; u < 4; ++u) {
        acc.x = fmaf(vA[u], bf_lo(rA[u].x), acc.x);
        acc.y = fmaf(vA[u], bf_hi(rA[u].x), acc.y);
        acc.z = fmaf(vA[u], bf_lo(rA[u].y), acc.z);
        acc.w = fmaf(vA[u], bf_hi(rA[u].y), acc.w);
    }
    if (haveB) {
        #pragma unroll
        for (int u = 0; u < 4; ++u) {
            acc.x = fmaf(vB[u], bf_lo(rB[u].x), acc.x);
            acc.y = fmaf(vB[u], bf_hi(rB[u].x), acc.y);
            acc.z = fmaf(vB[u], bf_lo(rB[u].y), acc.z);
            acc.w = fmaf(vB[u], bf_hi(rB[u].y), acc.w);
        }
    }
    for (int e = e0 + 32; e < e1; e += 16) {
        #pragma unroll
        for (int u = 0; u < 4; ++u) {
            const int  ce = e + 4 * u + g;
            const bool ok = ce < e1;
            const uint_t p = cv[ok ? ce : eclamp];
            const int   c = (int)(p >> 16);
            const float v = ok ? bf_lo(p) : 0.f;
            const uint2 r = *(const uint2*)(tin + (size_t)c * D + l * 4);
            acc.x = fmaf(v, bf_lo(r.x), acc.x);
            acc.y = fmaf(v, bf_hi(r.x), acc.y);
            acc.z = fmaf(v, bf_lo(r.y), acc.z);
            acc.w = fmaf(v, bf_hi(r.y), acc.w);
        }
    }

    #pragma unroll
    for (int off = 16; off < 64; off <<= 1) {
        acc.x += __shfl_xor(acc.x, off, 64);
        acc.y += __shfl_xor(acc.y, off, 64);
        acc.z += __shfl_xor(acc.z, off, 64);
        acc.w += __shfl_xor(acc.w, off, 64);
    }

    if (g == 0) {
        const size_t base = (size_t)row * D + (size_t)l * 4;
        float4 o = *(const float4*)(out + base);
        o.x += acc.x; o.y += acc.y; o.z += acc.z; o.w += acc.w;
        *(float4*)(out + base) = o;
    }
}

// ---------------------------------------------------------------------------
extern "C" void kernel_launch(void* const* d_in, const int* in_sizes, int n_in,
                              void* d_out, int out_size, void* d_ws, size_t ws_size,
                              hipStream_t stream) {
    const float* x        = (const float*)d_in[0];  // [N, 64]
    const float* edge_val = (const float*)d_in[1];  // [E]
    const float* W        = (const float*)d_in[2];  // [4, 64, 64]
    const float* b        = (const float*)d_in[3];  // [4, 64]
    const int* edge_row   = (const int*)d_in[4];    // sorted
    const int* edge_col   = (const int*)d_in[5];
    const int* event_type = (const int*)d_in[6];    // [N] (int32 on device)
    float* out = (float*)d_out;

    // ws: cv uint32[E] | row_ptr[N+2] | tA bf16[N*64] | tB bf16[N*64]
    char* p = (char*)d_ws;
    uint_t*   cv      = (uint_t*)p;                  p += (size_t)N_EDGES * 4;
    int*      row_ptr = (int*)p;                     p += (size_t)(N_NODES + 2) * 4;
    p = (char*)(((uintptr_t)p + 15) & ~(uintptr_t)15);
    ushort_t* tA      = (ushort_t*)p;                p += (size_t)N_NODES * D * 2;
    ushort_t* tB      = (ushort_t*)p;

    prep_kernel<<<(N_EDGES + 255) / 256, 256, 0, stream>>>(
        edge_row, edge_col, edge_val, row_ptr, cv);

    // head 0 linear: x (masked) -> tA
    linear_elu_kernel<<<1024, 256, 0, stream>>>(x, W, b, event_type, tA);

    // fused: spmm(t_i) -> out ; linear_{i+1}(h, in-register/LDS) -> t_{i+1}
    // grid 4096 blocks = 16384 waves (~3 rows/wave): occupancy for gather
    // latency hiding, W tile amortized over rows and L2-resident.
    fused_kernel<1, 1><<<4096, 256, 0, stream>>>(
        tA, tB, W + 1 * D * D, b + 1 * D, cv, row_ptr, out);
    fused_kernel<0, 1><<<4096, 256, 0, stream>>>(
        tB, tA, W + 2 * D * D, b + 2 * D, cv, row_ptr, out);
    fused_kernel<0, 1><<<4096, 256, 0, stream>>>(
        tA, tB, W + 3 * D * D, b + 3 * D, cv, row_ptr, out);

    // head 4: spmm only (R7 structure, 1 row/wave)
    spmm_kernel<<<(N_NODES * 64 + 255) / 256, 256, 0, stream>>>(
        tB, cv, row_ptr, out);
}

// Round 13
// 193.672 us; speedup vs baseline: 1.1230x; 1.1230x over previous
//
#include <hip/hip_runtime.h>
#include <math.h>

#define N_NODES 50000
#define D       64
#define N_EDGES 800000
#define N_HEAD  4

typedef unsigned short ushort_t;
typedef unsigned int   uint_t;

// bf16 <-> fp32 bit helpers (RNE on pack)
__device__ __forceinline__ float bf_lo(uint_t u) {
    return __uint_as_float(u << 16);
}
__device__ __forceinline__ float bf_hi(uint_t u) {
    return __uint_as_float(u & 0xffff0000u);
}
__device__ __forceinline__ ushort_t f2bf(float f) {
    uint_t u = __float_as_uint(f);
    u += 0x7fffu + ((u >> 16) & 1u);   // round-to-nearest-even
    return (ushort_t)(u >> 16);
}

// ---------------------------------------------------------------------------
// prep: cv[e] = (col<<16) | bf16(val)  (col < 50000 fits 16 bits);
//       row_ptr[r] = lower_bound(edge_row, r) (edge_row sorted)
// ---------------------------------------------------------------------------
__global__ void prep_kernel(const int* __restrict__ edge_row,
                            const int* __restrict__ edge_col,
                            const float* __restrict__ edge_val,
                            int* __restrict__ row_ptr,
                            uint_t* __restrict__ cv) {
    const int i = blockIdx.x * blockDim.x + threadIdx.x;
    if (i < N_EDGES)
        cv[i] = ((uint_t)edge_col[i] << 16) | (uint_t)f2bf(edge_val[i]);
    if (i <= N_NODES) {
        int lo = 0, hi = N_EDGES;
        while (lo < hi) {
            int mid = (lo + hi) >> 1;
            if (edge_row[mid] < i) lo = mid + 1; else hi = mid;
        }
        row_ptr[i] = lo;
    }
}

// ---------------------------------------------------------------------------
// head-0 linear: t[n][j] = bf16( elu( sum_k (mask? x[n][k]:0)*W[j][k] + b[j] ) )
// lane j holds W[j][*] in 64 VGPRs; row data via wave-uniform scalar loads.
// ---------------------------------------------------------------------------
__global__ __launch_bounds__(256) void linear_elu_kernel(
        const float* __restrict__ in,
        const float* __restrict__ W,
        const float* __restrict__ b,
        const int*  __restrict__ et,
        ushort_t* __restrict__ t) {
    const int lane = threadIdx.x & 63;
    const int wid  = (blockIdx.x * blockDim.x + threadIdx.x) >> 6;
    const int nwav = (gridDim.x * blockDim.x) >> 6;

    float4 w4[16];
    {
        const float4* wp = (const float4*)(W + lane * D);
        #pragma unroll
        for (int i = 0; i < 16; ++i) w4[i] = wp[i];
    }
    const float* w = (const float*)w4;
    const float bj = b[lane];

    for (int row0 = wid; row0 < N_NODES; row0 += nwav) {
        const int row = __builtin_amdgcn_readfirstlane(row0);
        float acc = bj;
        if (et[row] != 0) {
            const float* rp = in + (size_t)row * D;
            #pragma unroll
            for (int k = 0; k < D; ++k)
                acc = fmaf(rp[k], w[k], acc);
        }
        const float e = (acc > 0.f) ? acc : expm1f(acc);
        t[(size_t)row * D + lane] = f2bf(e);
    }
}

// ---------------------------------------------------------------------------
// Fused spmm + next-head linear with a 2-deep CROSS-ROW software pipeline.
// Per iteration (row r):
//   issue gathers for r (meta arrived, was issued at r-1)
//   issue meta loads for r+1 (row_ptr arrived, was issued at r-1)
//   issue row_ptr loads for r+2
//   consume r's gathers -> FMA, reduce, out RMW, LDS-broadcast epilogue
// In-order vmcnt: consuming r's gathers leaves the later-issued r+1 loads
// in flight, so the metadata round is hidden under FMA/epilogue work.
// W stays in 64 VGPRs (R6/R12 proved reload-per-row is fatal); grid 1024
// (R12 proved bigger grids can't raise occupancy past the VGPR bin).
// ---------------------------------------------------------------------------
template<int FIRST, int DO_LINEAR>
__global__ __launch_bounds__(256) void fused_kernel(
        const ushort_t* __restrict__ tin,   // bf16 [N][64]
        ushort_t* __restrict__ tout,        // bf16 [N][64]
        const float* __restrict__ W,        // next head's W
        const float* __restrict__ bvec,
        const uint_t* __restrict__ cv,      // (col<<16)|bf16(val)
        const int*  __restrict__ row_ptr,
        float* __restrict__ out) {
    __shared__ float rowbuf[4][64];
    const int tid   = threadIdx.x;
    const int lane  = tid & 63;
    const int wslot = tid >> 6;
    const int g     = lane >> 4;
    const int l     = lane & 15;
    const int wid   = (blockIdx.x * blockDim.x + tid) >> 6;
    const int nwav  = (gridDim.x * blockDim.x) >> 6;

    float4 w4[16];
    float bj = 0.f;
    if (DO_LINEAR) {
        const float4* wp = (const float4*)(W + lane * D);
        #pragma unroll
        for (int i = 0; i < 16; ++i) w4[i] = wp[i];
        bj = bvec[lane];
    }
    const float* w = (const float*)w4;

    int row = wid;
    if (row >= N_NODES) return;

    // ---- pipeline prologue: row 0's bounds + meta; row 1's bounds ----
    int e0c = row_ptr[row];
    int e1c = row_ptr[row + 1];
    uint_t mc[8];
    {
        const int eclamp = (e1c > 0) ? e1c - 1 : 0;
        #pragma unroll
        for (int u = 0; u < 8; ++u) {
            const int ce = e0c + 4 * u + g;
            mc[u] = cv[(ce < e1c) ? ce : eclamp];
        }
    }
    int nxt = row + nwav;
    int e0n = 0, e1n = 0;
    if (nxt < N_NODES) { e0n = row_ptr[nxt]; e1n = row_ptr[nxt + 1]; }

    while (row < N_NODES) {
        const int srow = __builtin_amdgcn_readfirstlane(row);
        const size_t base = (size_t)srow * D + (size_t)l * 4;
        const bool haveB = (e0c + 16) < e1c;   // wave-uniform

        // decode meta for current row
        float vA[4], vB[4];
        int   cA[4], cB[4];
        #pragma unroll
        for (int u = 0; u < 4; ++u) {
            const int ce = e0c + 4 * u + g;
            cA[u] = (int)(mc[u] >> 16);
            vA[u] = (ce < e1c) ? bf_lo(mc[u]) : 0.f;
        }
        #pragma unroll
        for (int u = 0; u < 4; ++u) {
            const int ce = e0c + 16 + 4 * u + g;
            cB[u] = (int)(mc[4 + u] >> 16);
            vB[u] = (ce < e1c) ? bf_lo(mc[4 + u]) : 0.f;
        }

        // issue current row's gathers
        uint2 rA[4], rB[4];
        #pragma unroll
        for (int u = 0; u < 4; ++u)
            rA[u] = *(const uint2*)(tin + (size_t)cA[u] * D + l * 4);
        if (haveB) {
            #pragma unroll
            for (int u = 0; u < 4; ++u)
                rB[u] = *(const uint2*)(tin + (size_t)cB[u] * D + l * 4);
        }

        // out-RMW old value, early issue
        float4 oldo = {0.f, 0.f, 0.f, 0.f};
        if (!FIRST && g == 0) oldo = *(const float4*)(out + base);

        // issue NEXT row's meta (bounds arrived last iteration)
        uint_t mn[8];
        const bool has_next = nxt < N_NODES;   // wave-uniform
        if (has_next) {
            const int eclampn = (e1n > 0) ? e1n - 1 : 0;
            #pragma unroll
            for (int u = 0; u < 8; ++u) {
                const int ce = e0n + 4 * u + g;
                mn[u] = cv[(ce < e1n) ? ce : eclampn];
            }
        }
        // issue next-next row's bounds
        const int nn = nxt + nwav;
        int e0nn = 0, e1nn = 0;
        if (nn < N_NODES) { e0nn = row_ptr[nn]; e1nn = row_ptr[nn + 1]; }

        // consume current row's gathers
        float4 acc = {0.f, 0.f, 0.f, 0.f};
        #pragma unroll
        for (int u = 0; u < 4; ++u) {
            acc.x = fmaf(vA[u], bf_lo(rA[u].x), acc.x);
            acc.y = fmaf(vA[u], bf_hi(rA[u].x), acc.y);
            acc.z = fmaf(vA[u], bf_lo(rA[u].y), acc.z);
            acc.w = fmaf(vA[u], bf_hi(rA[u].y), acc.w);
        }
        if (haveB) {
            #pragma unroll
            for (int u = 0; u < 4; ++u) {
                acc.x = fmaf(vB[u], bf_lo(rB[u].x), acc.x);
                acc.y = fmaf(vB[u], bf_hi(rB[u].x), acc.y);
                acc.z = fmaf(vB[u], bf_lo(rB[u].y), acc.z);
                acc.w = fmaf(vB[u], bf_hi(rB[u].y), acc.w);
            }
        }
        // rare tail: deg > 32 (dependent loads, ~1e-4 of rows)
        for (int e = e0c + 32; e < e1c; e += 16) {
            const int eclamp = e1c - 1;
            #pragma unroll
            for (int u = 0; u < 4; ++u) {
                const int  ce = e + 4 * u + g;
                const bool ok = ce < e1c;
                const uint_t p = cv[ok ? ce : eclamp];
                const int   c = (int)(p >> 16);
                const float v = ok ? bf_lo(p) : 0.f;
                const uint2 r = *(const uint2*)(tin + (size_t)c * D + l * 4);
                acc.x = fmaf(v, bf_lo(r.x), acc.x);
                acc.y = fmaf(v, bf_hi(r.x), acc.y);
                acc.z = fmaf(v, bf_lo(r.y), acc.z);
                acc.w = fmaf(v, bf_hi(r.y), acc.w);
            }
        }

        // reduce across the 4 groups (lane bits 4,5)
        #pragma unroll
        for (int off = 16; off < 64; off <<= 1) {
            acc.x += __shfl_xor(acc.x, off, 64);
            acc.y += __shfl_xor(acc.y, off, 64);
            acc.z += __shfl_xor(acc.z, off, 64);
            acc.w += __shfl_xor(acc.w, off, 64);
        }

        if (g == 0) {
            float4 o;
            o.x = acc.x + oldo.x; o.y = acc.y + oldo.y;
            o.z = acc.z + oldo.z; o.w = acc.w + oldo.w;
            *(float4*)(out + base) = o;
            if (DO_LINEAR)
                *(float4*)&rowbuf[wslot][l * 4] =
                    make_float4(acc.x, acc.y, acc.z, acc.w);
        }

        if (DO_LINEAR) {
            // same-wave LDS RAW: compiler inserts lgkmcnt wait (R11-proven)
            float lacc = bj;
            #pragma unroll
            for (int k = 0; k < 16; ++k) {
                const float4 r = *(const float4*)&rowbuf[wslot][k * 4];
                lacc = fmaf(r.x, w[4 * k + 0], lacc);
                lacc = fmaf(r.y, w[4 * k + 1], lacc);
                lacc = fmaf(r.z, w[4 * k + 2], lacc);
                lacc = fmaf(r.w, w[4 * k + 3], lacc);
            }
            const float eo = (lacc > 0.f) ? lacc : expm1f(lacc);
            tout[(size_t)srow * D + lane] = f2bf(eo);
        }

        // rotate pipeline state
        row = nxt; nxt = nn;
        e0c = e0n; e1c = e1n; e0n = e0nn; e1n = e1nn;
        #pragma unroll
        for (int u = 0; u < 8; ++u) mc[u] = mn[u];
    }
}

// ---------------------------------------------------------------------------
// head-4 spmm (no linear epilogue) — unmodified R7 structure, 1 row/wave.
// ---------------------------------------------------------------------------
__global__ __launch_bounds__(256) void spmm_kernel(
        const ushort_t* __restrict__ tin,
        const uint_t* __restrict__ cv,
        const int*   __restrict__ row_ptr,
        float* __restrict__ out) {
    const int lane = threadIdx.x & 63;
    const int g    = lane >> 4;
    const int l    = lane & 15;
    const int row0 = (blockIdx.x * blockDim.x + threadIdx.x) >> 6;
    if (row0 >= N_NODES) return;
    const int row = __builtin_amdgcn_readfirstlane(row0);

    const int e0 = row_ptr[row];
    const int e1 = row_ptr[row + 1];
    const int eclamp = (e1 > 0) ? e1 - 1 : 0;
    float4 acc = {0.f, 0.f, 0.f, 0.f};

    int   cA[4], cB[4];
    float vA[4], vB[4];
    uint2 rA[4], rB[4];
    const bool haveB = (e0 + 16) < e1;

    #pragma unroll
    for (int u = 0; u < 4; ++u) {
        const int  ce = e0 + 4 * u + g;
        const bool ok = ce < e1;
        const uint_t p = cv[ok ? ce : eclamp];
        cA[u] = (int)(p >> 16);
        vA[u] = ok ? bf_lo(p) : 0.f;
    }
    if (haveB) {
        #pragma unroll
        for (int u = 0; u < 4; ++u) {
            const int  ce = e0 + 16 + 4 * u + g;
            const bool ok = ce < e1;
            const uint_t p = cv[ok ? ce : eclamp];
            cB[u] = (int)(p >> 16);
            vB[u] = ok ? bf_lo(p) : 0.f;
        }
    }
    #pragma unroll
    for (int u = 0; u < 4; ++u)
        rA[u] = *(const uint2*)(tin + (size_t)cA[u] * D + l * 4);
    if (haveB) {
        #pragma unroll
        for (int u = 0; u < 4; ++u)
            rB[u] = *(const uint2*)(tin + (size_t)cB[u] * D + l * 4);
    }
    #pragma unroll
    for (int u = 0; u < 4; ++u) {
        acc.x = fmaf(vA[u], bf_lo(rA[u].x), acc.x);
        acc.y = fmaf(vA[u], bf_hi(rA[u].x), acc.y);
        acc.z = fmaf(vA[u], bf_lo(rA[u].y), acc.z);
        acc.w = fmaf(vA[u], bf_hi(rA[u].y), acc.w);
    }
    if (haveB) {
        #pragma unroll
        for (int u = 0; u < 4; ++u) {
            acc.x = fmaf(vB[u], bf_lo(rB[u].x), acc.x);
            acc.y = fmaf(vB[u], bf_hi(rB[u].x), acc.y);
            acc.z = fmaf(vB[u], bf_lo(rB[u].y), acc.z);
            acc.w = fmaf(vB[u], bf_hi(rB[u].y), acc.w);
        }
    }
    for (int e = e0 + 32; e < e1; e += 16) {
        #pragma unroll
        for (int u = 0; u < 4; ++u) {
            const int  ce = e + 4 * u + g;
            const bool ok = ce < e1;
            const uint_t p = cv[ok ? ce : eclamp];
            const int   c = (int)(p >> 16);
            const float v = ok ? bf_lo(p) : 0.f;
            const uint2 r = *(const uint2*)(tin + (size_t)c * D + l * 4);
            acc.x = fmaf(v, bf_lo(r.x), acc.x);
            acc.y = fmaf(v, bf_hi(r.x), acc.y);
            acc.z = fmaf(v, bf_lo(r.y), acc.z);
            acc.w = fmaf(v, bf_hi(r.y), acc.w);
        }
    }

    #pragma unroll
    for (int off = 16; off < 64; off <<= 1) {
        acc.x += __shfl_xor(acc.x, off, 64);
        acc.y += __shfl_xor(acc.y, off, 64);
        acc.z += __shfl_xor(acc.z, off, 64);
        acc.w += __shfl_xor(acc.w, off, 64);
    }

    if (g == 0) {
        const size_t base = (size_t)row * D + (size_t)l * 4;
        float4 o = *(const float4*)(out + base);
        o.x += acc.x; o.y += acc.y; o.z += acc.z; o.w += acc.w;
        *(float4*)(out + base) = o;
    }
}

// ---------------------------------------------------------------------------
extern "C" void kernel_launch(void* const* d_in, const int* in_sizes, int n_in,
                              void* d_out, int out_size, void* d_ws, size_t ws_size,
                              hipStream_t stream) {
    const float* x        = (const float*)d_in[0];  // [N, 64]
    const float* edge_val = (const float*)d_in[1];  // [E]
    const float* W        = (const float*)d_in[2];  // [4, 64, 64]
    const float* b        = (const float*)d_in[3];  // [4, 64]
    const int* edge_row   = (const int*)d_in[4];    // sorted
    const int* edge_col   = (const int*)d_in[5];
    const int* event_type = (const int*)d_in[6];    // [N] (int32 on device)
    float* out = (float*)d_out;

    // ws: cv uint32[E] | row_ptr[N+2] | tA bf16[N*64] | tB bf16[N*64]
    char* p = (char*)d_ws;
    uint_t*   cv      = (uint_t*)p;                  p += (size_t)N_EDGES * 4;
    int*      row_ptr = (int*)p;                     p += (size_t)(N_NODES + 2) * 4;
    p = (char*)(((uintptr_t)p + 15) & ~(uintptr_t)15);
    ushort_t* tA      = (ushort_t*)p;                p += (size_t)N_NODES * D * 2;
    ushort_t* tB      = (ushort_t*)p;

    prep_kernel<<<(N_EDGES + 255) / 256, 256, 0, stream>>>(
        edge_row, edge_col, edge_val, row_ptr, cv);

    // head 0 linear: x (masked) -> tA
    linear_elu_kernel<<<1024, 256, 0, stream>>>(x, W, b, event_type, tA);

    // fused: spmm(t_i) -> out ; linear_{i+1} -> t_{i+1}; grid 1024 (R11 best)
    fused_kernel<1, 1><<<1024, 256, 0, stream>>>(
        tA, tB, W + 1 * D * D, b + 1 * D, cv, row_ptr, out);
    fused_kernel<0, 1><<<1024, 256, 0, stream>>>(
        tB, tA, W + 2 * D * D, b + 2 * D, cv, row_ptr, out);
    fused_kernel<0, 1><<<1024, 256, 0, stream>>>(
        tA, tB, W + 3 * D * D, b + 3 * D, cv, row_ptr, out);

    // head 4: spmm only (R7 structure, 1 row/wave)
    spmm_kernel<<<(N_NODES * 64 + 255) / 256, 256, 0, stream>>>(
        tB, cv, row_ptr, out);
}